// Round 5
// baseline (1381.625 us; speedup 1.0000x reference)
//
#include <hip/hip_runtime.h>
#include <math.h>

// ManifoldAttentionNoAttn — fp32, round 4 (fusion round, corrected PC buffer).
// vs round 3:
//  * k_zfin folded into k_sgemm (A-staging sums 4 partials + gelu inline)
//  * k_ycopy deleted: k_covT<0> reads Y = xp[:,:,:64] directly (V0 = E)
//  * k_yfin deleted: k_covT<1>, k_scales, k_tn sum the 4 K-chunk partials at
//    load time; Y buffer removed; covT writes its T-split partials to PC
//    (separate from PB to avoid cross-block RAW)
//  * 33 -> 27 dispatches
// B=4, T=2048, D=1024, RANK=SHIFT_RANK=64, EPS=1e-5, LAM=0.05, RHO=0.9.

#define BB 4
#define TT 2048
#define DD 1024
#define RR 64
#define NROWS (BB*TT)
#define NR ((size_t)NROWS * RR)          // 524288: one K-chunk partial plane

#define CP(m) (((m) >> 3) * 12 + ((m) & 7))

static __device__ __forceinline__ float gelu_f(float v) {
    return 0.5f * v * (1.0f + erff(v * 0.70710678118654752f));
}
static __device__ __forceinline__ float sgnf(float v) {
    return (v > 0.f) ? 1.f : ((v < 0.f) ? -1.f : 0.f);
}

// ======================= thin GEMM: M x 1024 times 1024 x 64, K-split 4.
__global__ __launch_bounds__(256) void k_xpV_part(
    const float* __restrict__ A, const float* __restrict__ V, float* __restrict__ Pp)
{
    __shared__ __align__(16) float xs[32][196];
    __shared__ __align__(16) float vs[32][68];
    const int tid = threadIdx.x;
    const int mblk = blockIdx.x & 63;
    const int c = blockIdx.x >> 6;
    const int row0 = mblk * 128;
    const int b = mblk >> 4;
    const float* Vb = V + (size_t)b * DD * RR;
    const int tm = tid & 15, rm = tid >> 4;
    float acc[8][4];
#pragma unroll
    for (int i = 0; i < 8; i++)
#pragma unroll
        for (int j = 0; j < 4; j++) acc[i][j] = 0.f;

    for (int ks = 0; ks < 8; ks++) {
        const int koff = c * 256 + ks * 32;
#pragma unroll
        for (int i = 0; i < 4; i++) {
            int f4 = i * 256 + tid;
            int m = f4 >> 3, kq = (f4 & 7) * 4;
            float4 v = *reinterpret_cast<const float4*>(A + (size_t)(row0 + m) * DD + koff + kq);
            int mc = CP(m);
            xs[kq + 0][mc] = v.x; xs[kq + 1][mc] = v.y; xs[kq + 2][mc] = v.z; xs[kq + 3][mc] = v.w;
        }
#pragma unroll
        for (int i = 0; i < 2; i++) {
            int f4 = i * 256 + tid;
            int kk = f4 >> 4, r4 = (f4 & 15) * 4;
            *reinterpret_cast<float4*>(&vs[kk][r4]) =
                *reinterpret_cast<const float4*>(Vb + (size_t)(koff + kk) * RR + r4);
        }
        __syncthreads();
#pragma unroll 8
        for (int kk = 0; kk < 32; kk++) {
            float4 a0 = *reinterpret_cast<const float4*>(&xs[kk][12 * tm]);
            float4 a1 = *reinterpret_cast<const float4*>(&xs[kk][12 * tm + 4]);
            float4 bv = *reinterpret_cast<const float4*>(&vs[kk][4 * rm]);
            float av[8] = {a0.x,a0.y,a0.z,a0.w,a1.x,a1.y,a1.z,a1.w};
#pragma unroll
            for (int i = 0; i < 8; i++) {
                acc[i][0] += av[i] * bv.x; acc[i][1] += av[i] * bv.y;
                acc[i][2] += av[i] * bv.z; acc[i][3] += av[i] * bv.w;
            }
        }
        __syncthreads();
    }
    float* P = Pp + (size_t)c * NR;
#pragma unroll
    for (int i = 0; i < 8; i++) {
        float4 o = make_float4(acc[i][0], acc[i][1], acc[i][2], acc[i][3]);
        *reinterpret_cast<float4*>(P + (size_t)(row0 + 8 * tm + i) * RR + 4 * rm) = o;
    }
}

__global__ __launch_bounds__(256) void k_zin_part(
    const float* __restrict__ x, const float* __restrict__ w_in, float* __restrict__ Pp)
{
    __shared__ __align__(16) float xs[32][196];
    __shared__ __align__(16) float vs[32][68];
    const int tid = threadIdx.x;
    const int mblk = blockIdx.x & 63;
    const int c = blockIdx.x >> 6;
    const int row0 = mblk * 128;
    const int tm = tid & 15, rm = tid >> 4;
    float acc[8][4];
#pragma unroll
    for (int i = 0; i < 8; i++)
#pragma unroll
        for (int j = 0; j < 4; j++) acc[i][j] = 0.f;

    for (int ks = 0; ks < 8; ks++) {
        const int koff = c * 256 + ks * 32;
#pragma unroll
        for (int i = 0; i < 4; i++) {
            int f4 = i * 256 + tid;
            int m = f4 >> 3, kq = (f4 & 7) * 4;
            float4 v = *reinterpret_cast<const float4*>(x + (size_t)(row0 + m) * DD + koff + kq);
            int mc = CP(m);
            xs[kq + 0][mc] = v.x; xs[kq + 1][mc] = v.y; xs[kq + 2][mc] = v.z; xs[kq + 3][mc] = v.w;
        }
#pragma unroll
        for (int i = 0; i < 2; i++) {
            int f4 = i * 256 + tid;
            int r = f4 >> 3, kq = (f4 & 7) * 4;
            float4 v = *reinterpret_cast<const float4*>(w_in + (size_t)r * DD + koff + kq);
            vs[kq + 0][r] = v.x; vs[kq + 1][r] = v.y; vs[kq + 2][r] = v.z; vs[kq + 3][r] = v.w;
        }
        __syncthreads();
#pragma unroll 8
        for (int kk = 0; kk < 32; kk++) {
            float4 a0 = *reinterpret_cast<const float4*>(&xs[kk][12 * tm]);
            float4 a1 = *reinterpret_cast<const float4*>(&xs[kk][12 * tm + 4]);
            float4 bv = *reinterpret_cast<const float4*>(&vs[kk][4 * rm]);
            float av[8] = {a0.x,a0.y,a0.z,a0.w,a1.x,a1.y,a1.z,a1.w};
#pragma unroll
            for (int i = 0; i < 8; i++) {
                acc[i][0] += av[i] * bv.x; acc[i][1] += av[i] * bv.y;
                acc[i][2] += av[i] * bv.z; acc[i][3] += av[i] * bv.w;
            }
        }
        __syncthreads();
    }
    float* P = Pp + (size_t)c * NR;
#pragma unroll
    for (int i = 0; i < 8; i++) {
        float4 o = make_float4(acc[i][0], acc[i][1], acc[i][2], acc[i][3]);
        *reinterpret_cast<float4*>(P + (size_t)(row0 + 8 * tm + i) * RR + 4 * rm) = o;
    }
}

// ======================= s = gelu_sum(z-partials) @ w_out_s^T + b_s ; xp = x - anchor + s
__global__ __launch_bounds__(256) void k_sgemm(
    const float* __restrict__ Pp, const float* __restrict__ x,
    const float* __restrict__ w_out_s, const float* __restrict__ b_s,
    float* __restrict__ xp, float* __restrict__ s_out)
{
    __shared__ __align__(16) float As[32][196];
    __shared__ __align__(16) float Bs[32][132];
    const int tid = threadIdx.x;
    const int row0 = (blockIdx.x >> 3) * 128;
    const int col0 = (blockIdx.x & 7) * 128;
    const int tm = tid & 15, tg = tid >> 4;
    float acc[8][8];
#pragma unroll
    for (int i = 0; i < 8; i++)
#pragma unroll
        for (int j = 0; j < 8; j++) acc[i][j] = 0.f;

    for (int k0 = 0; k0 < RR; k0 += 32) {
#pragma unroll
        for (int i = 0; i < 4; i++) {
            int f4 = i * 256 + tid;
            int m = f4 >> 3, kq = (f4 & 7) * 4;
            size_t base = (size_t)(row0 + m) * RR + k0 + kq;
            float4 a  = *reinterpret_cast<const float4*>(Pp + base);
            float4 bq = *reinterpret_cast<const float4*>(Pp + base + NR);
            float4 cq = *reinterpret_cast<const float4*>(Pp + base + 2 * NR);
            float4 dq = *reinterpret_cast<const float4*>(Pp + base + 3 * NR);
            int mc = CP(m);
            As[kq + 0][mc] = gelu_f(a.x + bq.x + cq.x + dq.x);
            As[kq + 1][mc] = gelu_f(a.y + bq.y + cq.y + dq.y);
            As[kq + 2][mc] = gelu_f(a.z + bq.z + cq.z + dq.z);
            As[kq + 3][mc] = gelu_f(a.w + bq.w + cq.w + dq.w);
        }
#pragma unroll
        for (int i = 0; i < 4; i++) {
            int f4 = i * 256 + tid;
            int n = f4 >> 3, kq = (f4 & 7) * 4;
            float4 v = *reinterpret_cast<const float4*>(w_out_s + (size_t)(col0 + n) * RR + k0 + kq);
            Bs[kq + 0][n] = v.x; Bs[kq + 1][n] = v.y; Bs[kq + 2][n] = v.z; Bs[kq + 3][n] = v.w;
        }
        __syncthreads();
#pragma unroll 4
        for (int k = 0; k < 32; k++) {
            float4 a0 = *reinterpret_cast<const float4*>(&As[k][12 * tm]);
            float4 a1 = *reinterpret_cast<const float4*>(&As[k][12 * tm + 4]);
            float4 b0 = *reinterpret_cast<const float4*>(&Bs[k][8 * tg]);
            float4 b1 = *reinterpret_cast<const float4*>(&Bs[k][8 * tg + 4]);
            float av[8] = {a0.x,a0.y,a0.z,a0.w,a1.x,a1.y,a1.z,a1.w};
            float bv[8] = {b0.x,b0.y,b0.z,b0.w,b1.x,b1.y,b1.z,b1.w};
#pragma unroll
            for (int i = 0; i < 8; i++)
#pragma unroll
                for (int j = 0; j < 8; j++) acc[i][j] += av[i] * bv[j];
        }
        __syncthreads();
    }
    const int r8 = row0 + 8 * tm, c8 = col0 + 8 * tg;
    float4 bs0 = *reinterpret_cast<const float4*>(b_s + c8);
    float4 bs1 = *reinterpret_cast<const float4*>(b_s + c8 + 4);
#pragma unroll
    for (int i = 0; i < 8; i++) {
        size_t off = (size_t)(r8 + i) * DD + c8;
        float4 x0 = *reinterpret_cast<const float4*>(x + off);
        float4 x1 = *reinterpret_cast<const float4*>(x + off + 4);
        float4 s0, s1, p0, p1;
        s0.x = acc[i][0] + bs0.x; s0.y = acc[i][1] + bs0.y;
        s0.z = acc[i][2] + bs0.z; s0.w = acc[i][3] + bs0.w;
        s1.x = acc[i][4] + bs1.x; s1.y = acc[i][5] + bs1.y;
        s1.z = acc[i][6] + bs1.z; s1.w = acc[i][7] + bs1.w;
        p0.x = x0.x + s0.x - ((c8 + 0) == 0 ? 1.f : 0.f);
        p0.y = x0.y + s0.y; p0.z = x0.z + s0.z; p0.w = x0.w + s0.w;
        p1.x = x1.x + s1.x; p1.y = x1.y + s1.y; p1.z = x1.z + s1.z; p1.w = x1.w + s1.w;
        *reinterpret_cast<float4*>(s_out + off) = s0;
        *reinterpret_cast<float4*>(s_out + off + 4) = s1;
        *reinterpret_cast<float4*>(xp + off) = p0;
        *reinterpret_cast<float4*>(xp + off + 4) = p1;
    }
}

// ======================= covariance transpose product, T-split 8.
// MODE 0: Y from xp[:, :, :64] (it-0).  MODE 1: Y = sum of 4 partials in Pp.
// Output partials to Wp (must NOT alias Pp).
template<int MODE>
__global__ __launch_bounds__(256) void k_covT(
    const float* __restrict__ xp, const float* __restrict__ Pp, float* __restrict__ Wp)
{
    __shared__ __align__(16) float xs[32][196];
    __shared__ __align__(16) float ys[32][68];
    const int tid = threadIdx.x;
    const int tc = blockIdx.x >> 5;
    const int b  = (blockIdx.x >> 3) & 3;
    const int dblk = blockIdx.x & 7;
    const int d0 = dblk * 128;
    const float* xpb = xp + (size_t)b * TT * DD;
    const int dm = tid & 15, rm = tid >> 4;
    float acc[8][4];
#pragma unroll
    for (int i = 0; i < 8; i++)
#pragma unroll
        for (int j = 0; j < 4; j++) acc[i][j] = 0.f;

    for (int ks = 0; ks < 8; ks++) {
        const int toff = tc * 256 + ks * 32;
#pragma unroll
        for (int i = 0; i < 4; i++) {
            int f4 = i * 256 + tid;
            int ttl = f4 >> 5, dq = (f4 & 31) * 4;
            *reinterpret_cast<float4*>(&xs[ttl][CP(dq)]) =
                *reinterpret_cast<const float4*>(xpb + (size_t)(toff + ttl) * DD + d0 + dq);
        }
#pragma unroll
        for (int i = 0; i < 2; i++) {
            int f4 = i * 256 + tid;
            int ttl = f4 >> 4, r4 = (f4 & 15) * 4;
            float4 o;
            if constexpr (MODE == 0) {
                o = *reinterpret_cast<const float4*>(xpb + (size_t)(toff + ttl) * DD + r4);
            } else {
                size_t base = ((size_t)b * TT + toff + ttl) * RR + r4;
                float4 a  = *reinterpret_cast<const float4*>(Pp + base);
                float4 bq = *reinterpret_cast<const float4*>(Pp + base + NR);
                float4 cq = *reinterpret_cast<const float4*>(Pp + base + 2 * NR);
                float4 dq = *reinterpret_cast<const float4*>(Pp + base + 3 * NR);
                o = make_float4(a.x + bq.x + cq.x + dq.x, a.y + bq.y + cq.y + dq.y,
                                a.z + bq.z + cq.z + dq.z, a.w + bq.w + cq.w + dq.w);
            }
            *reinterpret_cast<float4*>(&ys[ttl][r4]) = o;
        }
        __syncthreads();
#pragma unroll 8
        for (int ttl = 0; ttl < 32; ttl++) {
            float4 a0 = *reinterpret_cast<const float4*>(&xs[ttl][12 * dm]);
            float4 a1 = *reinterpret_cast<const float4*>(&xs[ttl][12 * dm + 4]);
            float4 yv = *reinterpret_cast<const float4*>(&ys[ttl][4 * rm]);
            float av[8] = {a0.x,a0.y,a0.z,a0.w,a1.x,a1.y,a1.z,a1.w};
#pragma unroll
            for (int i = 0; i < 8; i++) {
                acc[i][0] += av[i] * yv.x; acc[i][1] += av[i] * yv.y;
                acc[i][2] += av[i] * yv.z; acc[i][3] += av[i] * yv.w;
            }
        }
        __syncthreads();
    }
    float* W = Wp + (size_t)(tc * BB + b) * DD * RR;
#pragma unroll
    for (int i = 0; i < 8; i++) {
        float4 o = make_float4(acc[i][0], acc[i][1], acc[i][2], acc[i][3]);
        *reinterpret_cast<float4*>(W + (size_t)(d0 + 8 * dm + i) * RR + 4 * rm) = o;
    }
}

// covfin: W = (sum_tc Wp)/T + eps*V ; fused gram partial Gp1[b][dblk]
template<bool FIRST>
__global__ __launch_bounds__(256) void k_covfin(
    const float* __restrict__ Wp, const float* __restrict__ V,
    float* __restrict__ W, float* __restrict__ Gp)
{
    __shared__ __align__(16) float Wt[128][68];
    const int tid = threadIdx.x;
    const int b = blockIdx.x >> 3;
    const int dblk = blockIdx.x & 7;
    const int d0 = dblk * 128;
    const float inv = 1.0f / 2048.0f;
#pragma unroll
    for (int i = 0; i < 8; i++) {
        int f4 = i * 256 + tid;
        int row = f4 >> 4, c4 = (f4 & 15) * 4;
        size_t off = (size_t)(d0 + row) * RR + c4;
        float4 s = make_float4(0.f, 0.f, 0.f, 0.f);
#pragma unroll
        for (int tc = 0; tc < 8; tc++) {
            float4 v = *reinterpret_cast<const float4*>(Wp + (size_t)(tc * BB + b) * DD * RR + off);
            s.x += v.x; s.y += v.y; s.z += v.z; s.w += v.w;
        }
        float4 vv;
        if constexpr (FIRST) {
            int d = d0 + row;
            vv.x = (d == c4 + 0) ? 1.f : 0.f;
            vv.y = (d == c4 + 1) ? 1.f : 0.f;
            vv.z = (d == c4 + 2) ? 1.f : 0.f;
            vv.w = (d == c4 + 3) ? 1.f : 0.f;
        } else {
            vv = *reinterpret_cast<const float4*>(V + (size_t)b * DD * RR + off);
        }
        float4 o = make_float4(s.x * inv + 1e-5f * vv.x, s.y * inv + 1e-5f * vv.y,
                               s.z * inv + 1e-5f * vv.z, s.w * inv + 1e-5f * vv.w);
        *reinterpret_cast<float4*>(W + (size_t)b * DD * RR + off) = o;
        *reinterpret_cast<float4*>(&Wt[row][c4]) = o;
    }
    __syncthreads();
    const int ti = tid & 15, tj = tid >> 4;
    float g[4][4];
#pragma unroll
    for (int i = 0; i < 4; i++)
#pragma unroll
        for (int j = 0; j < 4; j++) g[i][j] = 0.f;
    for (int row = 0; row < 128; row++) {
        float4 a = *reinterpret_cast<const float4*>(&Wt[row][4 * ti]);
        float4 c = *reinterpret_cast<const float4*>(&Wt[row][4 * tj]);
        float av[4] = {a.x,a.y,a.z,a.w}, cv[4] = {c.x,c.y,c.z,c.w};
#pragma unroll
        for (int i = 0; i < 4; i++)
#pragma unroll
            for (int j = 0; j < 4; j++) g[i][j] += av[i] * cv[j];
    }
    float* G = Gp + (size_t)(b * 8 + dblk) * RR * RR;
#pragma unroll
    for (int i = 0; i < 4; i++) {
        float4 o = make_float4(g[i][0], g[i][1], g[i][2], g[i][3]);
        *reinterpret_cast<float4*>(G + (size_t)(4 * ti + i) * RR + 4 * tj) = o;
    }
}

// ======================= applyA: cholesky+inverse of sum(Gp1) in-block,
// Out = In * L^-T, fused gram of Out -> Gp2.
__global__ __launch_bounds__(256) void k_applyA(
    const float* __restrict__ In, const float* __restrict__ GpIn,
    float* __restrict__ Out, float* __restrict__ GpOut)
{
    __shared__ __align__(16) float aT[64][68];
    __shared__ __align__(16) float li[64][68];
    __shared__ __align__(16) float ins[64][196];
    const int tid = threadIdx.x;
    const int b = blockIdx.x >> 3;
    const int dblk = blockIdx.x & 7;
    const int d0 = dblk * 128;

#pragma unroll
    for (int q = 0; q < 4; q++) {
        int f4 = q * 256 + tid;
        int i = f4 >> 4, c4 = (f4 & 15) * 4;
        float4 s = make_float4(0.f, 0.f, 0.f, 0.f);
#pragma unroll
        for (int p = 0; p < 8; p++) {
            float4 v = *reinterpret_cast<const float4*>(GpIn + (size_t)(b * 8 + p) * RR * RR + i * RR + c4);
            s.x += v.x; s.y += v.y; s.z += v.z; s.w += v.w;
        }
        *reinterpret_cast<float4*>(&aT[i][c4]) = s;
    }
    const float* Inb = In + (size_t)b * DD * RR;
#pragma unroll
    for (int i = 0; i < 8; i++) {
        int f4 = i * 256 + tid;
        int m = f4 >> 4, k4 = (f4 & 15) * 4;
        float4 v = *reinterpret_cast<const float4*>(Inb + (size_t)(d0 + m) * RR + k4);
        int mc = CP(m);
        ins[k4 + 0][mc] = v.x; ins[k4 + 1][mc] = v.y; ins[k4 + 2][mc] = v.z; ins[k4 + 3][mc] = v.w;
    }
    __syncthreads();

    if (tid < 64) {
        const int t = tid;
        for (int j = 0; j < 64; j++) {
            float v = 0.f;
            if (t >= j) {
                v = aT[j][t];
                for (int i = 0; i < j; i++) v -= aT[i][t] * aT[i][j];
            }
            float vj = __shfl(v, j);
            float dg = sqrtf(vj);
            if (t >= j) aT[j][t] = (t == j) ? dg : v / dg;
        }
        for (int i = 0; i < 64; i++) {
            float s2 = 0.f;
            for (int k = 0; k < i; k++) s2 += aT[k][i] * li[k][t];
            float dg = aT[i][i];
            li[i][t] = (i < t) ? 0.f : ((i == t) ? 1.0f / dg : -s2 / dg);
        }
    }
    __syncthreads();

    float (*ls)[68] = aT;
#pragma unroll
    for (int q = 0; q < 16; q++) {
        int f = q * 256 + tid;
        int i = f >> 6, r = f & 63;
        ls[i][r] = li[r][i];
    }
    __syncthreads();

    const int mi = tid & 15, ri = tid >> 4;
    float acc[8][4];
#pragma unroll
    for (int i = 0; i < 8; i++)
#pragma unroll
        for (int j = 0; j < 4; j++) acc[i][j] = 0.f;
#pragma unroll 8
    for (int kk = 0; kk < 64; kk++) {
        float4 a0 = *reinterpret_cast<const float4*>(&ins[kk][12 * mi]);
        float4 a1 = *reinterpret_cast<const float4*>(&ins[kk][12 * mi + 4]);
        float4 lv = *reinterpret_cast<const float4*>(&ls[kk][4 * ri]);
        float av[8] = {a0.x,a0.y,a0.z,a0.w,a1.x,a1.y,a1.z,a1.w};
#pragma unroll
        for (int i = 0; i < 8; i++) {
            acc[i][0] += av[i] * lv.x; acc[i][1] += av[i] * lv.y;
            acc[i][2] += av[i] * lv.z; acc[i][3] += av[i] * lv.w;
        }
    }
    float* Ob = Out + (size_t)b * DD * RR;
#pragma unroll
    for (int i = 0; i < 8; i++) {
        float4 o = make_float4(acc[i][0], acc[i][1], acc[i][2], acc[i][3]);
        *reinterpret_cast<float4*>(Ob + (size_t)(d0 + 8 * mi + i) * RR + 4 * ri) = o;
    }

    __syncthreads();
    float (*qs)[68] = reinterpret_cast<float(*)[68]>(&ins[0][0]);
#pragma unroll
    for (int i = 0; i < 8; i++) {
        float4 o = make_float4(acc[i][0], acc[i][1], acc[i][2], acc[i][3]);
        *reinterpret_cast<float4*>(&qs[8 * mi + i][4 * ri]) = o;
    }
    __syncthreads();
    const int ti = tid & 15, tj = tid >> 4;
    float g[4][4];
#pragma unroll
    for (int i = 0; i < 4; i++)
#pragma unroll
        for (int j = 0; j < 4; j++) g[i][j] = 0.f;
    for (int row = 0; row < 128; row++) {
        float4 a = *reinterpret_cast<const float4*>(&qs[row][4 * ti]);
        float4 c = *reinterpret_cast<const float4*>(&qs[row][4 * tj]);
        float av[4] = {a.x,a.y,a.z,a.w}, cv[4] = {c.x,c.y,c.z,c.w};
#pragma unroll
        for (int i = 0; i < 4; i++)
#pragma unroll
            for (int j = 0; j < 4; j++) g[i][j] += av[i] * cv[j];
    }
    float* G = GpOut + (size_t)(b * 8 + dblk) * RR * RR;
#pragma unroll
    for (int i = 0; i < 4; i++) {
        float4 o = make_float4(g[i][0], g[i][1], g[i][2], g[i][3]);
        *reinterpret_cast<float4*>(G + (size_t)(4 * ti + i) * RR + 4 * tj) = o;
    }
}

// ======================= applyN: Newton re-orthonormalization (pass 2)
__global__ __launch_bounds__(256) void k_applyN(
    const float* __restrict__ In, const float* __restrict__ Gp2,
    float* __restrict__ Out)
{
    __shared__ __align__(16) float ls[64][68];
    __shared__ __align__(16) float ins[64][196];
    const int tid = threadIdx.x;
    const int b = blockIdx.x >> 3;
    const int dblk = blockIdx.x & 7;
    const int d0 = dblk * 128;

#pragma unroll
    for (int q = 0; q < 4; q++) {
        int f4 = q * 256 + tid;
        int r = f4 >> 4, i4 = (f4 & 15) * 4;
        float4 s = make_float4(0.f, 0.f, 0.f, 0.f);
#pragma unroll
        for (int p = 0; p < 8; p++) {
            float4 v = *reinterpret_cast<const float4*>(Gp2 + (size_t)(b * 8 + p) * RR * RR + r * RR + i4);
            s.x += v.x; s.y += v.y; s.z += v.z; s.w += v.w;
        }
        float gv[4] = {s.x, s.y, s.z, s.w};
#pragma unroll
        for (int j = 0; j < 4; j++) {
            int i = i4 + j;
            float g = gv[j];
            ls[i][r] = (i < r) ? -g : ((i == r) ? (1.5f - 0.5f * g) : 0.f);
        }
    }
    const float* Inb = In + (size_t)b * DD * RR;
#pragma unroll
    for (int i = 0; i < 8; i++) {
        int f4 = i * 256 + tid;
        int m = f4 >> 4, k4 = (f4 & 15) * 4;
        float4 v = *reinterpret_cast<const float4*>(Inb + (size_t)(d0 + m) * RR + k4);
        int mc = CP(m);
        ins[k4 + 0][mc] = v.x; ins[k4 + 1][mc] = v.y; ins[k4 + 2][mc] = v.z; ins[k4 + 3][mc] = v.w;
    }
    __syncthreads();

    const int mi = tid & 15, ri = tid >> 4;
    float acc[8][4];
#pragma unroll
    for (int i = 0; i < 8; i++)
#pragma unroll
        for (int j = 0; j < 4; j++) acc[i][j] = 0.f;
#pragma unroll 8
    for (int kk = 0; kk < 64; kk++) {
        float4 a0 = *reinterpret_cast<const float4*>(&ins[kk][12 * mi]);
        float4 a1 = *reinterpret_cast<const float4*>(&ins[kk][12 * mi + 4]);
        float4 lv = *reinterpret_cast<const float4*>(&ls[kk][4 * ri]);
        float av[8] = {a0.x,a0.y,a0.z,a0.w,a1.x,a1.y,a1.z,a1.w};
#pragma unroll
        for (int i = 0; i < 8; i++) {
            acc[i][0] += av[i] * lv.x; acc[i][1] += av[i] * lv.y;
            acc[i][2] += av[i] * lv.z; acc[i][3] += av[i] * lv.w;
        }
    }
    float* Ob = Out + (size_t)b * DD * RR;
#pragma unroll
    for (int i = 0; i < 8; i++) {
        float4 o = make_float4(acc[i][0], acc[i][1], acc[i][2], acc[i][3]);
        *reinterpret_cast<float4*>(Ob + (size_t)(d0 + 8 * mi + i) * RR + 4 * ri) = o;
    }
}

// ======================= scales[b,r] = sqrt(sum_t (sum_c Pp)^2 + EPS)
__global__ __launch_bounds__(256) void k_scales(const float* __restrict__ Pp, float* __restrict__ scales)
{
    __shared__ float red[4][64];
    const int b = blockIdx.x, tid = threadIdx.x;
    const int r = tid & 63, q = tid >> 6;
    float s = 0.f;
    for (int t = q; t < TT; t += 4) {
        size_t base = ((size_t)b * TT + t) * RR + r;
        float v = Pp[base] + Pp[base + NR] + Pp[base + 2 * NR] + Pp[base + 3 * NR];
        s += v * v;
    }
    red[q][r] = s;
    __syncthreads();
    if (q == 0) scales[b * 64 + r] = sqrtf(red[0][r] + red[1][r] + red[2][r] + red[3][r] + 1e-5f);
}

// ======================= normalize(+sign) + softgelu + 2x spiral
__global__ __launch_bounds__(256) void k_tn(
    const float* __restrict__ Pp, const float* __restrict__ scales,
    const float* __restrict__ V, float* __restrict__ tn)
{
    const int tid = threadIdx.x;
    const int row = blockIdx.x * 4 + (tid >> 6);
    const int lane = tid & 63;
    const int b = row >> 11;
    size_t base = (size_t)row * RR + lane;
    float tr = Pp[base] + Pp[base + NR] + Pp[base + 2 * NR] + Pp[base + 3 * NR];
    float sgv = sgnf(V[(size_t)b * DD * RR + lane] + 1e-12f);
    float v = sgv * tr / scales[b * 64 + lane];
    float sg = sgnf(v);
    float a = fabsf(v) - 0.05f;
    v = sg * gelu_f(a);
    const float Cc = (float)0.9950041652780258;
    const float Ss = (float)0.09983341664682815;
#pragma unroll
    for (int it = 0; it < 2; it++) {
        float ss = v * v;
        ss += __shfl_xor(ss, 1);  ss += __shfl_xor(ss, 2);  ss += __shfl_xor(ss, 4);
        ss += __shfl_xor(ss, 8);  ss += __shfl_xor(ss, 16); ss += __shfl_xor(ss, 32);
        float rn = fmaxf(sqrtf(ss), 1e-8f);
        float radial = (6.0f - rn) * (v / rn);
        float p = __shfl_xor(v, 1);
        float rot = (lane & 1) ? (Ss * p + Cc * v) : (Cc * v - Ss * p);
        v = v + 0.1f * (rot - v + radial);
    }
    tn[(size_t)row * RR + lane] = v;
}

// ======================= AR(1), chunked, decay warm-up (rho^192 ~ 1.7e-9)
__global__ __launch_bounds__(64) void k_ar1p(const float* __restrict__ tn, float* __restrict__ tnf)
{
    const int b = blockIdx.x >> 3;
    const int chunk = blockIdx.x & 7;
    const int lane = threadIdx.x;
    const float* tb = tn + (size_t)b * TT * RR;
    float* fb = tnf + (size_t)b * TT * RR;
    const int c0 = chunk * 256;
    if (chunk == 0) {
        float y = tb[lane];
        fb[lane] = y;
        for (int t = 1; t < 256; t++) {
            float xv = tb[(size_t)t * RR + lane];
            y = 0.9f * y + 0.1f * xv;
            fb[(size_t)t * RR + lane] = y;
        }
    } else {
        const int t0 = c0 - 192;
        float y = tb[(size_t)t0 * RR + lane];
        for (int t = t0 + 1; t < c0 + 256; t++) {
            float xv = tb[(size_t)t * RR + lane];
            y = 0.9f * y + 0.1f * xv;
            if (t >= c0) fb[(size_t)t * RR + lane] = y;
        }
    }
}

// ======================= xh = (tnf*scales*sgn) @ V^T - s + anchor
__global__ __launch_bounds__(256) void k_xhat(
    const float* __restrict__ tnf, const float* __restrict__ scales,
    const float* __restrict__ V, const float* __restrict__ s_in, float* __restrict__ xh)
{
    __shared__ __align__(16) float As[32][196];
    __shared__ __align__(16) float Bs[32][132];
    const int tid = threadIdx.x;
    const int row0 = (blockIdx.x >> 3) * 128;
    const int col0 = (blockIdx.x & 7) * 128;
    const int b = row0 >> 11;
    const float* Vb = V + (size_t)b * DD * RR;
    const int tm = tid & 15, tg = tid >> 4;
    float acc[8][8];
#pragma unroll
    for (int i = 0; i < 8; i++)
#pragma unroll
        for (int j = 0; j < 8; j++) acc[i][j] = 0.f;

    for (int k0 = 0; k0 < RR; k0 += 32) {
#pragma unroll
        for (int i = 0; i < 4; i++) {
            int f4 = i * 256 + tid;
            int m = f4 >> 3, kq = (f4 & 7) * 4;
            float4 v = *reinterpret_cast<const float4*>(tnf + (size_t)(row0 + m) * RR + k0 + kq);
            float4 sc = *reinterpret_cast<const float4*>(scales + b * 64 + k0 + kq);
            float4 v0 = *reinterpret_cast<const float4*>(Vb + k0 + kq);
            float4 u;
            u.x = v.x * sc.x * sgnf(v0.x + 1e-12f);
            u.y = v.y * sc.y * sgnf(v0.y + 1e-12f);
            u.z = v.z * sc.z * sgnf(v0.z + 1e-12f);
            u.w = v.w * sc.w * sgnf(v0.w + 1e-12f);
            int mc = CP(m);
            As[kq + 0][mc] = u.x; As[kq + 1][mc] = u.y; As[kq + 2][mc] = u.z; As[kq + 3][mc] = u.w;
        }
#pragma unroll
        for (int i = 0; i < 4; i++) {
            int f4 = i * 256 + tid;
            int n = f4 >> 3, kq = (f4 & 7) * 4;
            float4 v = *reinterpret_cast<const float4*>(Vb + (size_t)(col0 + n) * RR + k0 + kq);
            Bs[kq + 0][n] = v.x; Bs[kq + 1][n] = v.y; Bs[kq + 2][n] = v.z; Bs[kq + 3][n] = v.w;
        }
        __syncthreads();
#pragma unroll 4
        for (int k = 0; k < 32; k++) {
            float4 a0 = *reinterpret_cast<const float4*>(&As[k][12 * tm]);
            float4 a1 = *reinterpret_cast<const float4*>(&As[k][12 * tm + 4]);
            float4 b0 = *reinterpret_cast<const float4*>(&Bs[k][8 * tg]);
            float4 b1 = *reinterpret_cast<const float4*>(&Bs[k][8 * tg + 4]);
            float av[8] = {a0.x,a0.y,a0.z,a0.w,a1.x,a1.y,a1.z,a1.w};
            float bv[8] = {b0.x,b0.y,b0.z,b0.w,b1.x,b1.y,b1.z,b1.w};
#pragma unroll
            for (int i = 0; i < 8; i++)
#pragma unroll
                for (int j = 0; j < 8; j++) acc[i][j] += av[i] * bv[j];
        }
        __syncthreads();
    }
    const int r8 = row0 + 8 * tm, c8 = col0 + 8 * tg;
#pragma unroll
    for (int i = 0; i < 8; i++) {
        size_t off = (size_t)(r8 + i) * DD + c8;
        float4 s0 = *reinterpret_cast<const float4*>(s_in + off);
        float4 s1 = *reinterpret_cast<const float4*>(s_in + off + 4);
        float4 o0, o1;
        o0.x = acc[i][0] - s0.x + ((c8 + 0) == 0 ? 1.f : 0.f);
        o0.y = acc[i][1] - s0.y; o0.z = acc[i][2] - s0.z; o0.w = acc[i][3] - s0.w;
        o1.x = acc[i][4] - s1.x; o1.y = acc[i][5] - s1.y;
        o1.z = acc[i][6] - s1.z; o1.w = acc[i][7] - s1.w;
        *reinterpret_cast<float4*>(xh + off) = o0;
        *reinterpret_cast<float4*>(xh + off + 4) = o1;
    }
}

// ======================= out = delta * tanh(scale * (xh @ w_out^T)) + bias
__global__ __launch_bounds__(256) void k_out(
    const float* __restrict__ xh, const float* __restrict__ w_out,
    const float* __restrict__ tn_scale, const float* __restrict__ tn_delta,
    const float* __restrict__ tn_bias, float* __restrict__ out)
{
    __shared__ __align__(16) float As[32][196];
    __shared__ __align__(16) float Bs[32][132];
    const int tid = threadIdx.x;
    const int row0 = (blockIdx.x >> 3) * 128;
    const int col0 = (blockIdx.x & 7) * 128;
    const int tm = tid & 15, tg = tid >> 4;
    float acc[8][8];
#pragma unroll
    for (int i = 0; i < 8; i++)
#pragma unroll
        for (int j = 0; j < 8; j++) acc[i][j] = 0.f;

    for (int k0 = 0; k0 < DD; k0 += 32) {
#pragma unroll
        for (int i = 0; i < 4; i++) {
            int f4 = i * 256 + tid;
            int m = f4 >> 3, kq = (f4 & 7) * 4;
            float4 v = *reinterpret_cast<const float4*>(xh + (size_t)(row0 + m) * DD + k0 + kq);
            int mc = CP(m);
            As[kq + 0][mc] = v.x; As[kq + 1][mc] = v.y; As[kq + 2][mc] = v.z; As[kq + 3][mc] = v.w;
        }
#pragma unroll
        for (int i = 0; i < 4; i++) {
            int f4 = i * 256 + tid;
            int n = f4 >> 3, kq = (f4 & 7) * 4;
            float4 v = *reinterpret_cast<const float4*>(w_out + (size_t)(col0 + n) * DD + k0 + kq);
            Bs[kq + 0][n] = v.x; Bs[kq + 1][n] = v.y; Bs[kq + 2][n] = v.z; Bs[kq + 3][n] = v.w;
        }
        __syncthreads();
#pragma unroll 4
        for (int k = 0; k < 32; k++) {
            float4 a0 = *reinterpret_cast<const float4*>(&As[k][12 * tm]);
            float4 a1 = *reinterpret_cast<const float4*>(&As[k][12 * tm + 4]);
            float4 b0 = *reinterpret_cast<const float4*>(&Bs[k][8 * tg]);
            float4 b1 = *reinterpret_cast<const float4*>(&Bs[k][8 * tg + 4]);
            float av[8] = {a0.x,a0.y,a0.z,a0.w,a1.x,a1.y,a1.z,a1.w};
            float bv[8] = {b0.x,b0.y,b0.z,b0.w,b1.x,b1.y,b1.z,b1.w};
#pragma unroll
            for (int i = 0; i < 8; i++)
#pragma unroll
                for (int j = 0; j < 8; j++) acc[i][j] += av[i] * bv[j];
        }
        __syncthreads();
    }
    const float ts = tn_scale[0];
#pragma unroll
    for (int i = 0; i < 8; i++) {
        int rrow = row0 + 8 * tm + i;
        int e0 = col0 + 8 * tg;
        float4 o0, o1;
        o0.x = tn_delta[e0 + 0] * tanhf(ts * acc[i][0]) + tn_bias[e0 + 0];
        o0.y = tn_delta[e0 + 1] * tanhf(ts * acc[i][1]) + tn_bias[e0 + 1];
        o0.z = tn_delta[e0 + 2] * tanhf(ts * acc[i][2]) + tn_bias[e0 + 2];
        o0.w = tn_delta[e0 + 3] * tanhf(ts * acc[i][3]) + tn_bias[e0 + 3];
        o1.x = tn_delta[e0 + 4] * tanhf(ts * acc[i][4]) + tn_bias[e0 + 4];
        o1.y = tn_delta[e0 + 5] * tanhf(ts * acc[i][5]) + tn_bias[e0 + 5];
        o1.z = tn_delta[e0 + 6] * tanhf(ts * acc[i][6]) + tn_bias[e0 + 6];
        o1.w = tn_delta[e0 + 7] * tanhf(ts * acc[i][7]) + tn_bias[e0 + 7];
        *reinterpret_cast<float4*>(out + (size_t)rrow * DD + e0) = o0;
        *reinterpret_cast<float4*>(out + (size_t)rrow * DD + e0 + 4) = o1;
    }
}

extern "C" void kernel_launch(void* const* d_in, const int* in_sizes, int n_in,
                              void* d_out, int out_size, void* d_ws, size_t ws_size,
                              hipStream_t stream) {
    const float* x        = (const float*)d_in[0];
    const float* w_in     = (const float*)d_in[1];
    const float* w_out_s  = (const float*)d_in[2];
    const float* b_s      = (const float*)d_in[3];
    const float* w_out    = (const float*)d_in[4];
    const float* tn_scale = (const float*)d_in[5];
    const float* tn_delta = (const float*)d_in[6];
    const float* tn_bias  = (const float*)d_in[7];
    float* out = (float*)d_out;

    float* ws   = (float*)d_ws;
    float* xp   = ws;                                   //  8,388,608 (reused as xh)
    float* s    = xp + (size_t)NROWS * DD;              //  8,388,608
    float* V    = s + (size_t)NROWS * DD;               //    262,144
    float* W    = V + (size_t)BB * DD * RR;             //    262,144
    float* PB   = W + (size_t)BB * DD * RR;             //  2,097,152 (K-chunk partials)
    float* PC   = PB + 4 * NR;                          //  2,097,152 (covT T-split partials)
    float* Gp1  = PC + 4 * NR;                          //    131,072
    float* Gp2  = Gp1 + (size_t)BB * 8 * RR * RR;       //    131,072
    float* sc   = Gp2 + (size_t)BB * 8 * RR * RR;       //        256
    float* tn   = sc + BB * RR;                         //    524,288
    float* tnf  = tn + NR;                              //    524,288

    k_zin_part<<<256, 256, 0, stream>>>(x, w_in, PB);
    k_sgemm<<<512, 256, 0, stream>>>(PB, x, w_out_s, b_s, xp, s);   // gelu fused

    // iteration 0: V0 = E => Y read from xp[:, :, :64]
    k_covT<0><<<256, 256, 0, stream>>>(xp, nullptr, PC);
    k_covfin<true><<<32, 256, 0, stream>>>(PC, nullptr, W, Gp1);
    k_applyA<<<32, 256, 0, stream>>>(W, Gp1, V, Gp2);
    k_applyN<<<32, 256, 0, stream>>>(V, Gp2, V);

    for (int it = 1; it < 4; ++it) {
        k_xpV_part<<<256, 256, 0, stream>>>(xp, V, PB);
        k_covT<1><<<256, 256, 0, stream>>>(xp, PB, PC);      // Y summed at load
        k_covfin<false><<<32, 256, 0, stream>>>(PC, V, W, Gp1);
        k_applyA<<<32, 256, 0, stream>>>(W, Gp1, V, Gp2);
        k_applyN<<<32, 256, 0, stream>>>(V, Gp2, V);
    }

    k_xpV_part<<<256, 256, 0, stream>>>(xp, V, PB);              // traces partials
    k_scales<<<4, 256, 0, stream>>>(PB, sc);
    k_tn<<<2048, 256, 0, stream>>>(PB, sc, V, tn);
    k_ar1p<<<32, 64, 0, stream>>>(tn, tnf);
    k_xhat<<<512, 256, 0, stream>>>(tnf, sc, V, s, xp);          // xh overwrites xp
    k_out<<<512, 256, 0, stream>>>(xp, w_out, tn_scale, tn_delta, tn_bias, out);
}

// Round 7
// 1071.370 us; speedup vs baseline: 1.2896x; 1.2896x over previous
//
#include <hip/hip_runtime.h>
#include <math.h>

// ManifoldAttentionNoAttn — round 6 (= round 5 resubmit; infra failure last round).
// vs round 4 (measured 1381 us, k_out=252 us fp32-VALU-bound):
//  * k_out -> split-bf16 MFMA (16x16x32): x = hi+lo bf16; C = Ah*Bh + Ah*Bl + Al*Bh.
//  * k_scales -> 128-block partial + finish.  * k_ar1p: 16 chunks/batch, warm-up 176.
//  * round-6 fix: __align__(16) on k_out_mfma LDS (uint4 stores require it).
// B=4, T=2048, D=1024, RANK=SHIFT_RANK=64, EPS=1e-5, LAM=0.05, RHO=0.9.

#define BB 4
#define TT 2048
#define DD 1024
#define RR 64
#define NROWS (BB*TT)
#define NR ((size_t)NROWS * RR)          // 524288: one K-chunk partial plane

#define CP(m) (((m) >> 3) * 12 + ((m) & 7))

typedef __attribute__((ext_vector_type(8))) short short8v;   // 8 bf16
typedef __attribute__((ext_vector_type(4))) float f32x4;

static __device__ __forceinline__ float gelu_f(float v) {
    return 0.5f * v * (1.0f + erff(v * 0.70710678118654752f));
}
static __device__ __forceinline__ float sgnf(float v) {
    return (v > 0.f) ? 1.f : ((v < 0.f) ? -1.f : 0.f);
}
static __device__ __forceinline__ unsigned short bf16_rne(float f, float* back) {
    unsigned u = __float_as_uint(f);
    unsigned r = (u + 0x7FFFu + ((u >> 16) & 1u)) >> 16;
    *back = __uint_as_float(r << 16);
    return (unsigned short)r;
}

// ======================= thin GEMM: M x 1024 times 1024 x 64, K-split 4.
__global__ __launch_bounds__(256) void k_xpV_part(
    const float* __restrict__ A, const float* __restrict__ V, float* __restrict__ Pp)
{
    __shared__ __align__(16) float xs[32][196];
    __shared__ __align__(16) float vs[32][68];
    const int tid = threadIdx.x;
    const int mblk = blockIdx.x & 63;
    const int c = blockIdx.x >> 6;
    const int row0 = mblk * 128;
    const int b = mblk >> 4;
    const float* Vb = V + (size_t)b * DD * RR;
    const int tm = tid & 15, rm = tid >> 4;
    float acc[8][4];
#pragma unroll
    for (int i = 0; i < 8; i++)
#pragma unroll
        for (int j = 0; j < 4; j++) acc[i][j] = 0.f;

    for (int ks = 0; ks < 8; ks++) {
        const int koff = c * 256 + ks * 32;
#pragma unroll
        for (int i = 0; i < 4; i++) {
            int f4 = i * 256 + tid;
            int m = f4 >> 3, kq = (f4 & 7) * 4;
            float4 v = *reinterpret_cast<const float4*>(A + (size_t)(row0 + m) * DD + koff + kq);
            int mc = CP(m);
            xs[kq + 0][mc] = v.x; xs[kq + 1][mc] = v.y; xs[kq + 2][mc] = v.z; xs[kq + 3][mc] = v.w;
        }
#pragma unroll
        for (int i = 0; i < 2; i++) {
            int f4 = i * 256 + tid;
            int kk = f4 >> 4, r4 = (f4 & 15) * 4;
            *reinterpret_cast<float4*>(&vs[kk][r4]) =
                *reinterpret_cast<const float4*>(Vb + (size_t)(koff + kk) * RR + r4);
        }
        __syncthreads();
#pragma unroll 8
        for (int kk = 0; kk < 32; kk++) {
            float4 a0 = *reinterpret_cast<const float4*>(&xs[kk][12 * tm]);
            float4 a1 = *reinterpret_cast<const float4*>(&xs[kk][12 * tm + 4]);
            float4 bv = *reinterpret_cast<const float4*>(&vs[kk][4 * rm]);
            float av[8] = {a0.x,a0.y,a0.z,a0.w,a1.x,a1.y,a1.z,a1.w};
#pragma unroll
            for (int i = 0; i < 8; i++) {
                acc[i][0] += av[i] * bv.x; acc[i][1] += av[i] * bv.y;
                acc[i][2] += av[i] * bv.z; acc[i][3] += av[i] * bv.w;
            }
        }
        __syncthreads();
    }
    float* P = Pp + (size_t)c * NR;
#pragma unroll
    for (int i = 0; i < 8; i++) {
        float4 o = make_float4(acc[i][0], acc[i][1], acc[i][2], acc[i][3]);
        *reinterpret_cast<float4*>(P + (size_t)(row0 + 8 * tm + i) * RR + 4 * rm) = o;
    }
}

__global__ __launch_bounds__(256) void k_zin_part(
    const float* __restrict__ x, const float* __restrict__ w_in, float* __restrict__ Pp)
{
    __shared__ __align__(16) float xs[32][196];
    __shared__ __align__(16) float vs[32][68];
    const int tid = threadIdx.x;
    const int mblk = blockIdx.x & 63;
    const int c = blockIdx.x >> 6;
    const int row0 = mblk * 128;
    const int tm = tid & 15, rm = tid >> 4;
    float acc[8][4];
#pragma unroll
    for (int i = 0; i < 8; i++)
#pragma unroll
        for (int j = 0; j < 4; j++) acc[i][j] = 0.f;

    for (int ks = 0; ks < 8; ks++) {
        const int koff = c * 256 + ks * 32;
#pragma unroll
        for (int i = 0; i < 4; i++) {
            int f4 = i * 256 + tid;
            int m = f4 >> 3, kq = (f4 & 7) * 4;
            float4 v = *reinterpret_cast<const float4*>(x + (size_t)(row0 + m) * DD + koff + kq);
            int mc = CP(m);
            xs[kq + 0][mc] = v.x; xs[kq + 1][mc] = v.y; xs[kq + 2][mc] = v.z; xs[kq + 3][mc] = v.w;
        }
#pragma unroll
        for (int i = 0; i < 2; i++) {
            int f4 = i * 256 + tid;
            int r = f4 >> 3, kq = (f4 & 7) * 4;
            float4 v = *reinterpret_cast<const float4*>(w_in + (size_t)r * DD + koff + kq);
            vs[kq + 0][r] = v.x; vs[kq + 1][r] = v.y; vs[kq + 2][r] = v.z; vs[kq + 3][r] = v.w;
        }
        __syncthreads();
#pragma unroll 8
        for (int kk = 0; kk < 32; kk++) {
            float4 a0 = *reinterpret_cast<const float4*>(&xs[kk][12 * tm]);
            float4 a1 = *reinterpret_cast<const float4*>(&xs[kk][12 * tm + 4]);
            float4 bv = *reinterpret_cast<const float4*>(&vs[kk][4 * rm]);
            float av[8] = {a0.x,a0.y,a0.z,a0.w,a1.x,a1.y,a1.z,a1.w};
#pragma unroll
            for (int i = 0; i < 8; i++) {
                acc[i][0] += av[i] * bv.x; acc[i][1] += av[i] * bv.y;
                acc[i][2] += av[i] * bv.z; acc[i][3] += av[i] * bv.w;
            }
        }
        __syncthreads();
    }
    float* P = Pp + (size_t)c * NR;
#pragma unroll
    for (int i = 0; i < 8; i++) {
        float4 o = make_float4(acc[i][0], acc[i][1], acc[i][2], acc[i][3]);
        *reinterpret_cast<float4*>(P + (size_t)(row0 + 8 * tm + i) * RR + 4 * rm) = o;
    }
}

// ======================= s = gelu_sum(z-partials) @ w_out_s^T + b_s ; xp = x - anchor + s
__global__ __launch_bounds__(256) void k_sgemm(
    const float* __restrict__ Pp, const float* __restrict__ x,
    const float* __restrict__ w_out_s, const float* __restrict__ b_s,
    float* __restrict__ xp, float* __restrict__ s_out)
{
    __shared__ __align__(16) float As[32][196];
    __shared__ __align__(16) float Bs[32][132];
    const int tid = threadIdx.x;
    const int row0 = (blockIdx.x >> 3) * 128;
    const int col0 = (blockIdx.x & 7) * 128;
    const int tm = tid & 15, tg = tid >> 4;
    float acc[8][8];
#pragma unroll
    for (int i = 0; i < 8; i++)
#pragma unroll
        for (int j = 0; j < 8; j++) acc[i][j] = 0.f;

    for (int k0 = 0; k0 < RR; k0 += 32) {
#pragma unroll
        for (int i = 0; i < 4; i++) {
            int f4 = i * 256 + tid;
            int m = f4 >> 3, kq = (f4 & 7) * 4;
            size_t base = (size_t)(row0 + m) * RR + k0 + kq;
            float4 a  = *reinterpret_cast<const float4*>(Pp + base);
            float4 bq = *reinterpret_cast<const float4*>(Pp + base + NR);
            float4 cq = *reinterpret_cast<const float4*>(Pp + base + 2 * NR);
            float4 dq = *reinterpret_cast<const float4*>(Pp + base + 3 * NR);
            int mc = CP(m);
            As[kq + 0][mc] = gelu_f(a.x + bq.x + cq.x + dq.x);
            As[kq + 1][mc] = gelu_f(a.y + bq.y + cq.y + dq.y);
            As[kq + 2][mc] = gelu_f(a.z + bq.z + cq.z + dq.z);
            As[kq + 3][mc] = gelu_f(a.w + bq.w + cq.w + dq.w);
        }
#pragma unroll
        for (int i = 0; i < 4; i++) {
            int f4 = i * 256 + tid;
            int n = f4 >> 3, kq = (f4 & 7) * 4;
            float4 v = *reinterpret_cast<const float4*>(w_out_s + (size_t)(col0 + n) * RR + k0 + kq);
            Bs[kq + 0][n] = v.x; Bs[kq + 1][n] = v.y; Bs[kq + 2][n] = v.z; Bs[kq + 3][n] = v.w;
        }
        __syncthreads();
#pragma unroll 4
        for (int k = 0; k < 32; k++) {
            float4 a0 = *reinterpret_cast<const float4*>(&As[k][12 * tm]);
            float4 a1 = *reinterpret_cast<const float4*>(&As[k][12 * tm + 4]);
            float4 b0 = *reinterpret_cast<const float4*>(&Bs[k][8 * tg]);
            float4 b1 = *reinterpret_cast<const float4*>(&Bs[k][8 * tg + 4]);
            float av[8] = {a0.x,a0.y,a0.z,a0.w,a1.x,a1.y,a1.z,a1.w};
            float bv[8] = {b0.x,b0.y,b0.z,b0.w,b1.x,b1.y,b1.z,b1.w};
#pragma unroll
            for (int i = 0; i < 8; i++)
#pragma unroll
                for (int j = 0; j < 8; j++) acc[i][j] += av[i] * bv[j];
        }
        __syncthreads();
    }
    const int r8 = row0 + 8 * tm, c8 = col0 + 8 * tg;
    float4 bs0 = *reinterpret_cast<const float4*>(b_s + c8);
    float4 bs1 = *reinterpret_cast<const float4*>(b_s + c8 + 4);
#pragma unroll
    for (int i = 0; i < 8; i++) {
        size_t off = (size_t)(r8 + i) * DD + c8;
        float4 x0 = *reinterpret_cast<const float4*>(x + off);
        float4 x1 = *reinterpret_cast<const float4*>(x + off + 4);
        float4 s0, s1, p0, p1;
        s0.x = acc[i][0] + bs0.x; s0.y = acc[i][1] + bs0.y;
        s0.z = acc[i][2] + bs0.z; s0.w = acc[i][3] + bs0.w;
        s1.x = acc[i][4] + bs1.x; s1.y = acc[i][5] + bs1.y;
        s1.z = acc[i][6] + bs1.z; s1.w = acc[i][7] + bs1.w;
        p0.x = x0.x + s0.x - ((c8 + 0) == 0 ? 1.f : 0.f);
        p0.y = x0.y + s0.y; p0.z = x0.z + s0.z; p0.w = x0.w + s0.w;
        p1.x = x1.x + s1.x; p1.y = x1.y + s1.y; p1.z = x1.z + s1.z; p1.w = x1.w + s1.w;
        *reinterpret_cast<float4*>(s_out + off) = s0;
        *reinterpret_cast<float4*>(s_out + off + 4) = s1;
        *reinterpret_cast<float4*>(xp + off) = p0;
        *reinterpret_cast<float4*>(xp + off + 4) = p1;
    }
}

// ======================= covariance transpose product, T-split 8.
template<int MODE>
__global__ __launch_bounds__(256) void k_covT(
    const float* __restrict__ xp, const float* __restrict__ Pp, float* __restrict__ Wp)
{
    __shared__ __align__(16) float xs[32][196];
    __shared__ __align__(16) float ys[32][68];
    const int tid = threadIdx.x;
    const int tc = blockIdx.x >> 5;
    const int b  = (blockIdx.x >> 3) & 3;
    const int dblk = blockIdx.x & 7;
    const int d0 = dblk * 128;
    const float* xpb = xp + (size_t)b * TT * DD;
    const int dm = tid & 15, rm = tid >> 4;
    float acc[8][4];
#pragma unroll
    for (int i = 0; i < 8; i++)
#pragma unroll
        for (int j = 0; j < 4; j++) acc[i][j] = 0.f;

    for (int ks = 0; ks < 8; ks++) {
        const int toff = tc * 256 + ks * 32;
#pragma unroll
        for (int i = 0; i < 4; i++) {
            int f4 = i * 256 + tid;
            int ttl = f4 >> 5, dq = (f4 & 31) * 4;
            *reinterpret_cast<float4*>(&xs[ttl][CP(dq)]) =
                *reinterpret_cast<const float4*>(xpb + (size_t)(toff + ttl) * DD + d0 + dq);
        }
#pragma unroll
        for (int i = 0; i < 2; i++) {
            int f4 = i * 256 + tid;
            int ttl = f4 >> 4, r4 = (f4 & 15) * 4;
            float4 o;
            if constexpr (MODE == 0) {
                o = *reinterpret_cast<const float4*>(xpb + (size_t)(toff + ttl) * DD + r4);
            } else {
                size_t base = ((size_t)b * TT + toff + ttl) * RR + r4;
                float4 a  = *reinterpret_cast<const float4*>(Pp + base);
                float4 bq = *reinterpret_cast<const float4*>(Pp + base + NR);
                float4 cq = *reinterpret_cast<const float4*>(Pp + base + 2 * NR);
                float4 dq = *reinterpret_cast<const float4*>(Pp + base + 3 * NR);
                o = make_float4(a.x + bq.x + cq.x + dq.x, a.y + bq.y + cq.y + dq.y,
                                a.z + bq.z + cq.z + dq.z, a.w + bq.w + cq.w + dq.w);
            }
            *reinterpret_cast<float4*>(&ys[ttl][r4]) = o;
        }
        __syncthreads();
#pragma unroll 8
        for (int ttl = 0; ttl < 32; ttl++) {
            float4 a0 = *reinterpret_cast<const float4*>(&xs[ttl][12 * dm]);
            float4 a1 = *reinterpret_cast<const float4*>(&xs[ttl][12 * dm + 4]);
            float4 yv = *reinterpret_cast<const float4*>(&ys[ttl][4 * rm]);
            float av[8] = {a0.x,a0.y,a0.z,a0.w,a1.x,a1.y,a1.z,a1.w};
#pragma unroll
            for (int i = 0; i < 8; i++) {
                acc[i][0] += av[i] * yv.x; acc[i][1] += av[i] * yv.y;
                acc[i][2] += av[i] * yv.z; acc[i][3] += av[i] * yv.w;
            }
        }
        __syncthreads();
    }
    float* W = Wp + (size_t)(tc * BB + b) * DD * RR;
#pragma unroll
    for (int i = 0; i < 8; i++) {
        float4 o = make_float4(acc[i][0], acc[i][1], acc[i][2], acc[i][3]);
        *reinterpret_cast<float4*>(W + (size_t)(d0 + 8 * dm + i) * RR + 4 * rm) = o;
    }
}

// covfin: W = (sum_tc Wp)/T + eps*V ; fused gram partial Gp1[b][dblk]
template<bool FIRST>
__global__ __launch_bounds__(256) void k_covfin(
    const float* __restrict__ Wp, const float* __restrict__ V,
    float* __restrict__ W, float* __restrict__ Gp)
{
    __shared__ __align__(16) float Wt[128][68];
    const int tid = threadIdx.x;
    const int b = blockIdx.x >> 3;
    const int dblk = blockIdx.x & 7;
    const int d0 = dblk * 128;
    const float inv = 1.0f / 2048.0f;
#pragma unroll
    for (int i = 0; i < 8; i++) {
        int f4 = i * 256 + tid;
        int row = f4 >> 4, c4 = (f4 & 15) * 4;
        size_t off = (size_t)(d0 + row) * RR + c4;
        float4 s = make_float4(0.f, 0.f, 0.f, 0.f);
#pragma unroll
        for (int tc = 0; tc < 8; tc++) {
            float4 v = *reinterpret_cast<const float4*>(Wp + (size_t)(tc * BB + b) * DD * RR + off);
            s.x += v.x; s.y += v.y; s.z += v.z; s.w += v.w;
        }
        float4 vv;
        if constexpr (FIRST) {
            int d = d0 + row;
            vv.x = (d == c4 + 0) ? 1.f : 0.f;
            vv.y = (d == c4 + 1) ? 1.f : 0.f;
            vv.z = (d == c4 + 2) ? 1.f : 0.f;
            vv.w = (d == c4 + 3) ? 1.f : 0.f;
        } else {
            vv = *reinterpret_cast<const float4*>(V + (size_t)b * DD * RR + off);
        }
        float4 o = make_float4(s.x * inv + 1e-5f * vv.x, s.y * inv + 1e-5f * vv.y,
                               s.z * inv + 1e-5f * vv.z, s.w * inv + 1e-5f * vv.w);
        *reinterpret_cast<float4*>(W + (size_t)b * DD * RR + off) = o;
        *reinterpret_cast<float4*>(&Wt[row][c4]) = o;
    }
    __syncthreads();
    const int ti = tid & 15, tj = tid >> 4;
    float g[4][4];
#pragma unroll
    for (int i = 0; i < 4; i++)
#pragma unroll
        for (int j = 0; j < 4; j++) g[i][j] = 0.f;
    for (int row = 0; row < 128; row++) {
        float4 a = *reinterpret_cast<const float4*>(&Wt[row][4 * ti]);
        float4 c = *reinterpret_cast<const float4*>(&Wt[row][4 * tj]);
        float av[4] = {a.x,a.y,a.z,a.w}, cv[4] = {c.x,c.y,c.z,c.w};
#pragma unroll
        for (int i = 0; i < 4; i++)
#pragma unroll
            for (int j = 0; j < 4; j++) g[i][j] += av[i] * cv[j];
    }
    float* G = Gp + (size_t)(b * 8 + dblk) * RR * RR;
#pragma unroll
    for (int i = 0; i < 4; i++) {
        float4 o = make_float4(g[i][0], g[i][1], g[i][2], g[i][3]);
        *reinterpret_cast<float4*>(G + (size_t)(4 * ti + i) * RR + 4 * tj) = o;
    }
}

// ======================= applyA: cholesky+inverse of sum(Gp1) in-block,
// Out = In * L^-T, fused gram of Out -> Gp2.
__global__ __launch_bounds__(256) void k_applyA(
    const float* __restrict__ In, const float* __restrict__ GpIn,
    float* __restrict__ Out, float* __restrict__ GpOut)
{
    __shared__ __align__(16) float aT[64][68];
    __shared__ __align__(16) float li[64][68];
    __shared__ __align__(16) float ins[64][196];
    const int tid = threadIdx.x;
    const int b = blockIdx.x >> 3;
    const int dblk = blockIdx.x & 7;
    const int d0 = dblk * 128;

#pragma unroll
    for (int q = 0; q < 4; q++) {
        int f4 = q * 256 + tid;
        int i = f4 >> 4, c4 = (f4 & 15) * 4;
        float4 s = make_float4(0.f, 0.f, 0.f, 0.f);
#pragma unroll
        for (int p = 0; p < 8; p++) {
            float4 v = *reinterpret_cast<const float4*>(GpIn + (size_t)(b * 8 + p) * RR * RR + i * RR + c4);
            s.x += v.x; s.y += v.y; s.z += v.z; s.w += v.w;
        }
        *reinterpret_cast<float4*>(&aT[i][c4]) = s;
    }
    const float* Inb = In + (size_t)b * DD * RR;
#pragma unroll
    for (int i = 0; i < 8; i++) {
        int f4 = i * 256 + tid;
        int m = f4 >> 4, k4 = (f4 & 15) * 4;
        float4 v = *reinterpret_cast<const float4*>(Inb + (size_t)(d0 + m) * RR + k4);
        int mc = CP(m);
        ins[k4 + 0][mc] = v.x; ins[k4 + 1][mc] = v.y; ins[k4 + 2][mc] = v.z; ins[k4 + 3][mc] = v.w;
    }
    __syncthreads();

    if (tid < 64) {
        const int t = tid;
        for (int j = 0; j < 64; j++) {
            float v = 0.f;
            if (t >= j) {
                v = aT[j][t];
                for (int i = 0; i < j; i++) v -= aT[i][t] * aT[i][j];
            }
            float vj = __shfl(v, j);
            float dg = sqrtf(vj);
            if (t >= j) aT[j][t] = (t == j) ? dg : v / dg;
        }
        for (int i = 0; i < 64; i++) {
            float s2 = 0.f;
            for (int k = 0; k < i; k++) s2 += aT[k][i] * li[k][t];
            float dg = aT[i][i];
            li[i][t] = (i < t) ? 0.f : ((i == t) ? 1.0f / dg : -s2 / dg);
        }
    }
    __syncthreads();

    float (*ls)[68] = aT;
#pragma unroll
    for (int q = 0; q < 16; q++) {
        int f = q * 256 + tid;
        int i = f >> 6, r = f & 63;
        ls[i][r] = li[r][i];
    }
    __syncthreads();

    const int mi = tid & 15, ri = tid >> 4;
    float acc[8][4];
#pragma unroll
    for (int i = 0; i < 8; i++)
#pragma unroll
        for (int j = 0; j < 4; j++) acc[i][j] = 0.f;
#pragma unroll 8
    for (int kk = 0; kk < 64; kk++) {
        float4 a0 = *reinterpret_cast<const float4*>(&ins[kk][12 * mi]);
        float4 a1 = *reinterpret_cast<const float4*>(&ins[kk][12 * mi + 4]);
        float4 lv = *reinterpret_cast<const float4*>(&ls[kk][4 * ri]);
        float av[8] = {a0.x,a0.y,a0.z,a0.w,a1.x,a1.y,a1.z,a1.w};
#pragma unroll
        for (int i = 0; i < 8; i++) {
            acc[i][0] += av[i] * lv.x; acc[i][1] += av[i] * lv.y;
            acc[i][2] += av[i] * lv.z; acc[i][3] += av[i] * lv.w;
        }
    }
    float* Ob = Out + (size_t)b * DD * RR;
#pragma unroll
    for (int i = 0; i < 8; i++) {
        float4 o = make_float4(acc[i][0], acc[i][1], acc[i][2], acc[i][3]);
        *reinterpret_cast<float4*>(Ob + (size_t)(d0 + 8 * mi + i) * RR + 4 * ri) = o;
    }

    __syncthreads();
    float (*qs)[68] = reinterpret_cast<float(*)[68]>(&ins[0][0]);
#pragma unroll
    for (int i = 0; i < 8; i++) {
        float4 o = make_float4(acc[i][0], acc[i][1], acc[i][2], acc[i][3]);
        *reinterpret_cast<float4*>(&qs[8 * mi + i][4 * ri]) = o;
    }
    __syncthreads();
    const int ti = tid & 15, tj = tid >> 4;
    float g[4][4];
#pragma unroll
    for (int i = 0; i < 4; i++)
#pragma unroll
        for (int j = 0; j < 4; j++) g[i][j] = 0.f;
    for (int row = 0; row < 128; row++) {
        float4 a = *reinterpret_cast<const float4*>(&qs[row][4 * ti]);
        float4 c = *reinterpret_cast<const float4*>(&qs[row][4 * tj]);
        float av[4] = {a.x,a.y,a.z,a.w}, cv[4] = {c.x,c.y,c.z,c.w};
#pragma unroll
        for (int i = 0; i < 4; i++)
#pragma unroll
            for (int j = 0; j < 4; j++) g[i][j] += av[i] * cv[j];
    }
    float* G = GpOut + (size_t)(b * 8 + dblk) * RR * RR;
#pragma unroll
    for (int i = 0; i < 4; i++) {
        float4 o = make_float4(g[i][0], g[i][1], g[i][2], g[i][3]);
        *reinterpret_cast<float4*>(G + (size_t)(4 * ti + i) * RR + 4 * tj) = o;
    }
}

// ======================= applyN: Newton re-orthonormalization (pass 2)
__global__ __launch_bounds__(256) void k_applyN(
    const float* __restrict__ In, const float* __restrict__ Gp2,
    float* __restrict__ Out)
{
    __shared__ __align__(16) float ls[64][68];
    __shared__ __align__(16) float ins[64][196];
    const int tid = threadIdx.x;
    const int b = blockIdx.x >> 3;
    const int dblk = blockIdx.x & 7;
    const int d0 = dblk * 128;

#pragma unroll
    for (int q = 0; q < 4; q++) {
        int f4 = q * 256 + tid;
        int r = f4 >> 4, i4 = (f4 & 15) * 4;
        float4 s = make_float4(0.f, 0.f, 0.f, 0.f);
#pragma unroll
        for (int p = 0; p < 8; p++) {
            float4 v = *reinterpret_cast<const float4*>(Gp2 + (size_t)(b * 8 + p) * RR * RR + r * RR + i4);
            s.x += v.x; s.y += v.y; s.z += v.z; s.w += v.w;
        }
        float gv[4] = {s.x, s.y, s.z, s.w};
#pragma unroll
        for (int j = 0; j < 4; j++) {
            int i = i4 + j;
            float g = gv[j];
            ls[i][r] = (i < r) ? -g : ((i == r) ? (1.5f - 0.5f * g) : 0.f);
        }
    }
    const float* Inb = In + (size_t)b * DD * RR;
#pragma unroll
    for (int i = 0; i < 8; i++) {
        int f4 = i * 256 + tid;
        int m = f4 >> 4, k4 = (f4 & 15) * 4;
        float4 v = *reinterpret_cast<const float4*>(Inb + (size_t)(d0 + m) * RR + k4);
        int mc = CP(m);
        ins[k4 + 0][mc] = v.x; ins[k4 + 1][mc] = v.y; ins[k4 + 2][mc] = v.z; ins[k4 + 3][mc] = v.w;
    }
    __syncthreads();

    const int mi = tid & 15, ri = tid >> 4;
    float acc[8][4];
#pragma unroll
    for (int i = 0; i < 8; i++)
#pragma unroll
        for (int j = 0; j < 4; j++) acc[i][j] = 0.f;
#pragma unroll 8
    for (int kk = 0; kk < 64; kk++) {
        float4 a0 = *reinterpret_cast<const float4*>(&ins[kk][12 * mi]);
        float4 a1 = *reinterpret_cast<const float4*>(&ins[kk][12 * mi + 4]);
        float4 lv = *reinterpret_cast<const float4*>(&ls[kk][4 * ri]);
        float av[8] = {a0.x,a0.y,a0.z,a0.w,a1.x,a1.y,a1.z,a1.w};
#pragma unroll
        for (int i = 0; i < 8; i++) {
            acc[i][0] += av[i] * lv.x; acc[i][1] += av[i] * lv.y;
            acc[i][2] += av[i] * lv.z; acc[i][3] += av[i] * lv.w;
        }
    }
    float* Ob = Out + (size_t)b * DD * RR;
#pragma unroll
    for (int i = 0; i < 8; i++) {
        float4 o = make_float4(acc[i][0], acc[i][1], acc[i][2], acc[i][3]);
        *reinterpret_cast<float4*>(Ob + (size_t)(d0 + 8 * mi + i) * RR + 4 * ri) = o;
    }
}

// ======================= scales: partial over 64-t chunks (128 blocks), then finish
__global__ __launch_bounds__(256) void k_scales_part(const float* __restrict__ Pp, float* __restrict__ part)
{
    __shared__ float red[4][64];
    const int b = blockIdx.x >> 5;
    const int tc = blockIdx.x & 31;
    const int tid = threadIdx.x;
    const int r = tid & 63, q = tid >> 6;
    float s = 0.f;
    for (int t = tc * 64 + q; t < tc * 64 + 64; t += 4) {
        size_t base = ((size_t)b * TT + t) * RR + r;
        float v = Pp[base] + Pp[base + NR] + Pp[base + 2 * NR] + Pp[base + 3 * NR];
        s += v * v;
    }
    red[q][r] = s;
    __syncthreads();
    if (q == 0) part[(size_t)blockIdx.x * 64 + r] = red[0][r] + red[1][r] + red[2][r] + red[3][r];
}

__global__ __launch_bounds__(256) void k_scales_fin(const float* __restrict__ part, float* __restrict__ scales)
{
    const int i = threadIdx.x;           // b = i>>6, r = i&63
    const int b = i >> 6, r = i & 63;
    float s = 0.f;
#pragma unroll
    for (int tc = 0; tc < 32; tc++) s += part[(size_t)(b * 32 + tc) * 64 + r];
    scales[i] = sqrtf(s + 1e-5f);
}

// ======================= normalize(+sign) + softgelu + 2x spiral
__global__ __launch_bounds__(256) void k_tn(
    const float* __restrict__ Pp, const float* __restrict__ scales,
    const float* __restrict__ V, float* __restrict__ tn)
{
    const int tid = threadIdx.x;
    const int row = blockIdx.x * 4 + (tid >> 6);
    const int lane = tid & 63;
    const int b = row >> 11;
    size_t base = (size_t)row * RR + lane;
    float tr = Pp[base] + Pp[base + NR] + Pp[base + 2 * NR] + Pp[base + 3 * NR];
    float sgv = sgnf(V[(size_t)b * DD * RR + lane] + 1e-12f);
    float v = sgv * tr / scales[b * 64 + lane];
    float sg = sgnf(v);
    float a = fabsf(v) - 0.05f;
    v = sg * gelu_f(a);
    const float Cc = (float)0.9950041652780258;
    const float Ss = (float)0.09983341664682815;
#pragma unroll
    for (int it = 0; it < 2; it++) {
        float ss = v * v;
        ss += __shfl_xor(ss, 1);  ss += __shfl_xor(ss, 2);  ss += __shfl_xor(ss, 4);
        ss += __shfl_xor(ss, 8);  ss += __shfl_xor(ss, 16); ss += __shfl_xor(ss, 32);
        float rn = fmaxf(sqrtf(ss), 1e-8f);
        float radial = (6.0f - rn) * (v / rn);
        float p = __shfl_xor(v, 1);
        float rot = (lane & 1) ? (Ss * p + Cc * v) : (Cc * v - Ss * p);
        v = v + 0.1f * (rot - v + radial);
    }
    tn[(size_t)row * RR + lane] = v;
}

// ======================= AR(1): 16 chunks of 128 per batch, warm-up 176
__global__ __launch_bounds__(64) void k_ar1p(const float* __restrict__ tn, float* __restrict__ tnf)
{
    const int b = blockIdx.x >> 4;
    const int chunk = blockIdx.x & 15;
    const int lane = threadIdx.x;
    const float* tb = tn + (size_t)b * TT * RR;
    float* fb = tnf + (size_t)b * TT * RR;
    const int c0 = chunk * 128;
    if (chunk == 0) {
        float y = tb[lane];
        fb[lane] = y;
        for (int t = 1; t < 128; t++) {
            float xv = tb[(size_t)t * RR + lane];
            y = 0.9f * y + 0.1f * xv;
            fb[(size_t)t * RR + lane] = y;
        }
    } else {
        int t0 = c0 - 176; if (t0 < 0) t0 = 0;
        float y = tb[(size_t)t0 * RR + lane];
        for (int t = t0 + 1; t < c0 + 128; t++) {
            float xv = tb[(size_t)t * RR + lane];
            y = 0.9f * y + 0.1f * xv;
            if (t >= c0) fb[(size_t)t * RR + lane] = y;
        }
    }
}

// ======================= xh = (tnf*scales*sgn) @ V^T - s + anchor
__global__ __launch_bounds__(256) void k_xhat(
    const float* __restrict__ tnf, const float* __restrict__ scales,
    const float* __restrict__ V, const float* __restrict__ s_in, float* __restrict__ xh)
{
    __shared__ __align__(16) float As[32][196];
    __shared__ __align__(16) float Bs[32][132];
    const int tid = threadIdx.x;
    const int row0 = (blockIdx.x >> 3) * 128;
    const int col0 = (blockIdx.x & 7) * 128;
    const int b = row0 >> 11;
    const float* Vb = V + (size_t)b * DD * RR;
    const int tm = tid & 15, tg = tid >> 4;
    float acc[8][8];
#pragma unroll
    for (int i = 0; i < 8; i++)
#pragma unroll
        for (int j = 0; j < 8; j++) acc[i][j] = 0.f;

    for (int k0 = 0; k0 < RR; k0 += 32) {
#pragma unroll
        for (int i = 0; i < 4; i++) {
            int f4 = i * 256 + tid;
            int m = f4 >> 3, kq = (f4 & 7) * 4;
            float4 v = *reinterpret_cast<const float4*>(tnf + (size_t)(row0 + m) * RR + k0 + kq);
            float4 sc = *reinterpret_cast<const float4*>(scales + b * 64 + k0 + kq);
            float4 v0 = *reinterpret_cast<const float4*>(Vb + k0 + kq);
            float4 u;
            u.x = v.x * sc.x * sgnf(v0.x + 1e-12f);
            u.y = v.y * sc.y * sgnf(v0.y + 1e-12f);
            u.z = v.z * sc.z * sgnf(v0.z + 1e-12f);
            u.w = v.w * sc.w * sgnf(v0.w + 1e-12f);
            int mc = CP(m);
            As[kq + 0][mc] = u.x; As[kq + 1][mc] = u.y; As[kq + 2][mc] = u.z; As[kq + 3][mc] = u.w;
        }
#pragma unroll
        for (int i = 0; i < 4; i++) {
            int f4 = i * 256 + tid;
            int n = f4 >> 3, kq = (f4 & 7) * 4;
            float4 v = *reinterpret_cast<const float4*>(Vb + (size_t)(col0 + n) * RR + k0 + kq);
            Bs[kq + 0][n] = v.x; Bs[kq + 1][n] = v.y; Bs[kq + 2][n] = v.z; Bs[kq + 3][n] = v.w;
        }
        __syncthreads();
#pragma unroll 4
        for (int k = 0; k < 32; k++) {
            float4 a0 = *reinterpret_cast<const float4*>(&As[k][12 * tm]);
            float4 a1 = *reinterpret_cast<const float4*>(&As[k][12 * tm + 4]);
            float4 b0 = *reinterpret_cast<const float4*>(&Bs[k][8 * tg]);
            float4 b1 = *reinterpret_cast<const float4*>(&Bs[k][8 * tg + 4]);
            float av[8] = {a0.x,a0.y,a0.z,a0.w,a1.x,a1.y,a1.z,a1.w};
            float bv[8] = {b0.x,b0.y,b0.z,b0.w,b1.x,b1.y,b1.z,b1.w};
#pragma unroll
            for (int i = 0; i < 8; i++)
#pragma unroll
                for (int j = 0; j < 8; j++) acc[i][j] += av[i] * bv[j];
        }
        __syncthreads();
    }
    const int r8 = row0 + 8 * tm, c8 = col0 + 8 * tg;
#pragma unroll
    for (int i = 0; i < 8; i++) {
        size_t off = (size_t)(r8 + i) * DD + c8;
        float4 s0 = *reinterpret_cast<const float4*>(s_in + off);
        float4 s1 = *reinterpret_cast<const float4*>(s_in + off + 4);
        float4 o0, o1;
        o0.x = acc[i][0] - s0.x + ((c8 + 0) == 0 ? 1.f : 0.f);
        o0.y = acc[i][1] - s0.y; o0.z = acc[i][2] - s0.z; o0.w = acc[i][3] - s0.w;
        o1.x = acc[i][4] - s1.x; o1.y = acc[i][5] - s1.y;
        o1.z = acc[i][6] - s1.z; o1.w = acc[i][7] - s1.w;
        *reinterpret_cast<float4*>(xh + off) = o0;
        *reinterpret_cast<float4*>(xh + off + 4) = o1;
    }
}

// ======================= split fp32 -> hi/lo bf16 (RNE)
__global__ __launch_bounds__(256) void k_split(
    const float* __restrict__ in, unsigned short* __restrict__ hi,
    unsigned short* __restrict__ lo, int n4)
{
    int i = blockIdx.x * 256 + threadIdx.x;
    if (i >= n4) return;
    float4 v = reinterpret_cast<const float4*>(in)[i];
    ushort4 h, l;
    float back;
    h.x = bf16_rne(v.x, &back); l.x = bf16_rne(v.x - back, &back);
    h.y = bf16_rne(v.y, &back); l.y = bf16_rne(v.y - back, &back);
    h.z = bf16_rne(v.z, &back); l.z = bf16_rne(v.z - back, &back);
    h.w = bf16_rne(v.w, &back); l.w = bf16_rne(v.w - back, &back);
    reinterpret_cast<ushort4*>(hi)[i] = h;
    reinterpret_cast<ushort4*>(lo)[i] = l;
}

// ======================= out = delta * tanh(scale * (xh @ w_out^T)) + bias
// split-bf16 MFMA 16x16x32: C = Ah*Bh + Ah*Bl + Al*Bh. Block 128x128, BK=32,
// 4 waves, wave tile 64x64 (4x4 frags). LDS tiles [row][32k] bf16, stride 40.
__global__ __launch_bounds__(256) void k_out_mfma(
    const unsigned short* __restrict__ Ahg, const unsigned short* __restrict__ Alg,
    const unsigned short* __restrict__ Bhg, const unsigned short* __restrict__ Blg,
    const float* __restrict__ tn_scale, const float* __restrict__ tn_delta,
    const float* __restrict__ tn_bias, float* __restrict__ out)
{
    __shared__ __align__(16) unsigned short Ah[128 * 40];
    __shared__ __align__(16) unsigned short Al[128 * 40];
    __shared__ __align__(16) unsigned short Bh[128 * 40];
    __shared__ __align__(16) unsigned short Bl[128 * 40];
    const int tid = threadIdx.x;
    const int row0 = (blockIdx.x >> 3) * 128;
    const int col0 = (blockIdx.x & 7) * 128;
    const int srow = tid >> 1, skh = (tid & 1) * 16;       // staging: 2 thr/row, 16 bf16 each
    const int lane = tid & 63, w = tid >> 6;
    const int wm = (w & 1) * 64, wn = (w >> 1) * 64;
    const int fr = lane & 15, kb = lane >> 4;

    f32x4 acc[4][4];
#pragma unroll
    for (int i = 0; i < 4; i++)
#pragma unroll
        for (int j = 0; j < 4; j++) acc[i][j] = (f32x4){0.f, 0.f, 0.f, 0.f};

    const size_t a_base = (size_t)(row0 + srow) * DD + skh;
    const size_t b_base = (size_t)(col0 + srow) * DD + skh;
    const int s_lds = srow * 40 + skh;

    for (int k0 = 0; k0 < DD; k0 += 32) {
        uint4 va0 = *reinterpret_cast<const uint4*>(Ahg + a_base + k0);
        uint4 va1 = *reinterpret_cast<const uint4*>(Ahg + a_base + k0 + 8);
        uint4 vb0 = *reinterpret_cast<const uint4*>(Alg + a_base + k0);
        uint4 vb1 = *reinterpret_cast<const uint4*>(Alg + a_base + k0 + 8);
        uint4 vc0 = *reinterpret_cast<const uint4*>(Bhg + b_base + k0);
        uint4 vc1 = *reinterpret_cast<const uint4*>(Bhg + b_base + k0 + 8);
        uint4 vd0 = *reinterpret_cast<const uint4*>(Blg + b_base + k0);
        uint4 vd1 = *reinterpret_cast<const uint4*>(Blg + b_base + k0 + 8);
        *reinterpret_cast<uint4*>(&Ah[s_lds]) = va0;
        *reinterpret_cast<uint4*>(&Ah[s_lds + 8]) = va1;
        *reinterpret_cast<uint4*>(&Al[s_lds]) = vb0;
        *reinterpret_cast<uint4*>(&Al[s_lds + 8]) = vb1;
        *reinterpret_cast<uint4*>(&Bh[s_lds]) = vc0;
        *reinterpret_cast<uint4*>(&Bh[s_lds + 8]) = vc1;
        *reinterpret_cast<uint4*>(&Bl[s_lds]) = vd0;
        *reinterpret_cast<uint4*>(&Bl[s_lds + 8]) = vd1;
        __syncthreads();

        short8v ah[4], al[4], bh[4], bl[4];
#pragma unroll
        for (int f = 0; f < 4; f++) {
            int ra = (wm + f * 16 + fr) * 40 + kb * 8;
            int rb = (wn + f * 16 + fr) * 40 + kb * 8;
            ah[f] = *reinterpret_cast<const short8v*>(&Ah[ra]);
            al[f] = *reinterpret_cast<const short8v*>(&Al[ra]);
            bh[f] = *reinterpret_cast<const short8v*>(&Bh[rb]);
            bl[f] = *reinterpret_cast<const short8v*>(&Bl[rb]);
        }
#pragma unroll
        for (int fm = 0; fm < 4; fm++)
#pragma unroll
            for (int fn = 0; fn < 4; fn++) {
                acc[fm][fn] = __builtin_amdgcn_mfma_f32_16x16x32_bf16(ah[fm], bh[fn], acc[fm][fn], 0, 0, 0);
                acc[fm][fn] = __builtin_amdgcn_mfma_f32_16x16x32_bf16(ah[fm], bl[fn], acc[fm][fn], 0, 0, 0);
                acc[fm][fn] = __builtin_amdgcn_mfma_f32_16x16x32_bf16(al[fm], bh[fn], acc[fm][fn], 0, 0, 0);
            }
        __syncthreads();
    }

    const float ts = tn_scale[0];
#pragma unroll
    for (int fn = 0; fn < 4; fn++) {
        int c = col0 + wn + fn * 16 + fr;
        float td = tn_delta[c], tbi = tn_bias[c];
#pragma unroll
        for (int fm = 0; fm < 4; fm++) {
            int r = row0 + wm + fm * 16 + kb * 4;
#pragma unroll
            for (int j = 0; j < 4; j++) {
                float v = acc[fm][fn][j];
                out[(size_t)(r + j) * DD + c] = td * tanhf(ts * v) + tbi;
            }
        }
    }
}

extern "C" void kernel_launch(void* const* d_in, const int* in_sizes, int n_in,
                              void* d_out, int out_size, void* d_ws, size_t ws_size,
                              hipStream_t stream) {
    const float* x        = (const float*)d_in[0];
    const float* w_in     = (const float*)d_in[1];
    const float* w_out_s  = (const float*)d_in[2];
    const float* b_s      = (const float*)d_in[3];
    const float* w_out    = (const float*)d_in[4];
    const float* tn_scale = (const float*)d_in[5];
    const float* tn_delta = (const float*)d_in[6];
    const float* tn_bias  = (const float*)d_in[7];
    float* out = (float*)d_out;

    float* ws   = (float*)d_ws;
    float* xp   = ws;                                   //  8,388,608 (reused as xh)
    float* s    = xp + (size_t)NROWS * DD;              //  8,388,608 (later: xh hi/lo bf16)
    float* V    = s + (size_t)NROWS * DD;               //    262,144
    float* W    = V + (size_t)BB * DD * RR;             //    262,144
    float* PB   = W + (size_t)BB * DD * RR;             //  2,097,152 (K-chunk partials)
    float* PC   = PB + 4 * NR;                          //  2,097,152 (covT partials; later w_out hi/lo)
    float* Gp1  = PC + 4 * NR;                          //    131,072 (later: scales partials)
    float* Gp2  = Gp1 + (size_t)BB * 8 * RR * RR;       //    131,072
    float* sc   = Gp2 + (size_t)BB * 8 * RR * RR;       //        256
    float* tn   = sc + BB * RR;                         //    524,288
    float* tnf  = tn + NR;                              //    524,288

    // bf16 overlays on dead buffers:
    unsigned short* xhH = (unsigned short*)s;                 // 16,777,216 B
    unsigned short* xhL = xhH + (size_t)NROWS * DD;           // 16,777,216 B (s = 33.5 MB total, fits)
    unsigned short* wH  = (unsigned short*)PC;                // 2,097,152 B
    unsigned short* wL  = wH + (size_t)DD * DD;               // 2,097,152 B (PC = 8.4 MB, fits)
    float* scpart = Gp1;                                      // 8,192 floats

    k_zin_part<<<256, 256, 0, stream>>>(x, w_in, PB);
    k_sgemm<<<512, 256, 0, stream>>>(PB, x, w_out_s, b_s, xp, s);   // gelu fused

    // iteration 0: V0 = E => Y read from xp[:, :, :64]
    k_covT<0><<<256, 256, 0, stream>>>(xp, nullptr, PC);
    k_covfin<true><<<32, 256, 0, stream>>>(PC, nullptr, W, Gp1);
    k_applyA<<<32, 256, 0, stream>>>(W, Gp1, V, Gp2);
    k_applyN<<<32, 256, 0, stream>>>(V, Gp2, V);

    for (int it = 1; it < 4; ++it) {
        k_xpV_part<<<256, 256, 0, stream>>>(xp, V, PB);
        k_covT<1><<<256, 256, 0, stream>>>(xp, PB, PC);      // Y summed at load
        k_covfin<false><<<32, 256, 0, stream>>>(PC, V, W, Gp1);
        k_applyA<<<32, 256, 0, stream>>>(W, Gp1, V, Gp2);
        k_applyN<<<32, 256, 0, stream>>>(V, Gp2, V);
    }

    k_xpV_part<<<256, 256, 0, stream>>>(xp, V, PB);              // traces partials
    k_scales_part<<<128, 256, 0, stream>>>(PB, scpart);
    k_scales_fin<<<1, 256, 0, stream>>>(scpart, sc);
    k_tn<<<2048, 256, 0, stream>>>(PB, sc, V, tn);
    k_ar1p<<<64, 64, 0, stream>>>(tn, tnf);
    k_xhat<<<512, 256, 0, stream>>>(tnf, sc, V, s, xp);          // xh overwrites xp (reads s)

    // split xh and w_out into bf16 hi/lo (overlay dead s / PC)
    k_split<<<8192, 256, 0, stream>>>(xp, xhH, xhL, 2097152);
    k_split<<<1024, 256, 0, stream>>>(w_out, wH, wL, 262144);
    k_out_mfma<<<512, 256, 0, stream>>>(xhH, xhL, wH, wL, tn_scale, tn_delta, tn_bias, out);
}